// Round 3
// baseline (8376.689 us; speedup 1.0000x reference)
//
#include <hip/hip_runtime.h>

// Round 2: diagnostic + correctness round. Pure-VALU fused MHA forward with
// ON-DEVICE input-dtype detection (fp32 vs bf16) — two prior rounds failed
// with output==memset-zero signature, so this round removes every uncertain
// construct (no MFMA builtins, no LDS-layout tricks) and resolves the dtype
// ambiguity at runtime.
//
// Pipeline: probe -> 3x vgemm (QKV proj, relu) -> vattn (causal online
// softmax) -> vgemm (out proj, relu) -> d_out.
// Intermediates: always bf16 in d_ws (flag int + 4 regions x 4M u16 = 32 MB).

using u16 = unsigned short;

static constexpr int S = 1024, Dm = 1024, NH = 16, HD = 64;

__device__ __forceinline__ float asf(unsigned int u) {
    union { unsigned int i; float f; } x; x.i = u; return x.f;
}
__device__ __forceinline__ float lo16(unsigned int u) { return asf(u << 16); }
__device__ __forceinline__ float hi16(unsigned int u) { return asf(u & 0xffff0000u); }
__device__ __forceinline__ float b2f(u16 v) { return asf(((unsigned int)v) << 16); }
__device__ __forceinline__ u16 f2b(float f) {
    union { float f; unsigned int i; } x; x.f = f;
    return (u16)((x.i + 0x7fffu + ((x.i >> 16) & 1u)) >> 16);  // RNE, finite
}

// ---------------------------------------------------------------------------
// Dtype probe on q ~ N(0,1). fp32 buffer: low u16 of each word is mantissa
// garbage -> as bf16, ~91% have |x|>16 or |x|<1e-6. bf16-pair buffer: low
// half is a genuine N(0,1) sample -> ~0%. flag=1 means inputs are fp32.
// ---------------------------------------------------------------------------
__global__ void probe_dtype(const unsigned int* __restrict__ q, int* __restrict__ flag) {
    int score = 0;
    for (int i = 0; i < 256; ++i) {
        const float a = fabsf(lo16(q[i]));
        if (a > 16.0f || a < 1e-6f) ++score;
    }
    *flag = (score > 128) ? 1 : 0;
}

// ---------------------------------------------------------------------------
// out = relu(A @ W^T + bias). A:[4096,1024], W:[1024,1024], bias:[1024].
// aF/wF/oF: that pointer follows the detected external dtype (else bf16).
// Thread (m=by, n=bx*256+tid) computes one output. A-row loads are
// wave-uniform (broadcast); W-row loads stream per-lane (W is L2-resident).
// ---------------------------------------------------------------------------
__global__ __launch_bounds__(256)
void vgemm(const void* __restrict__ A, const void* __restrict__ W,
           const void* __restrict__ bias, void* __restrict__ out,
           const int* __restrict__ flag, int aF, int wF, int oF)
{
    const int n = blockIdx.x * 256 + threadIdx.x;
    const int m = blockIdx.y;
    const int f = *flag;
    const bool a32 = (aF != 0) && (f != 0);
    const bool w32 = (wF != 0) && (f != 0);
    const bool o32 = (oF != 0) && (f != 0);

    const float*  Af = (const float*)A + (size_t)m * Dm;
    const u16*    Ab = (const u16*)A + (size_t)m * Dm;
    const float*  Wf = (const float*)W + (size_t)n * Dm;
    const u16*    Wb = (const u16*)W + (size_t)n * Dm;

    float acc = 0.0f;
    float av[8], wv[8];
    for (int k = 0; k < Dm; k += 8) {
        if (a32) {
            const float4 x = *(const float4*)(Af + k);
            const float4 y = *(const float4*)(Af + k + 4);
            av[0] = x.x; av[1] = x.y; av[2] = x.z; av[3] = x.w;
            av[4] = y.x; av[5] = y.y; av[6] = y.z; av[7] = y.w;
        } else {
            const uint4 u = *(const uint4*)(Ab + k);
            av[0] = lo16(u.x); av[1] = hi16(u.x); av[2] = lo16(u.y); av[3] = hi16(u.y);
            av[4] = lo16(u.z); av[5] = hi16(u.z); av[6] = lo16(u.w); av[7] = hi16(u.w);
        }
        if (w32) {
            const float4 x = *(const float4*)(Wf + k);
            const float4 y = *(const float4*)(Wf + k + 4);
            wv[0] = x.x; wv[1] = x.y; wv[2] = x.z; wv[3] = x.w;
            wv[4] = y.x; wv[5] = y.y; wv[6] = y.z; wv[7] = y.w;
        } else {
            const uint4 u = *(const uint4*)(Wb + k);
            wv[0] = lo16(u.x); wv[1] = hi16(u.x); wv[2] = lo16(u.y); wv[3] = hi16(u.y);
            wv[4] = lo16(u.z); wv[5] = hi16(u.z); wv[6] = lo16(u.w); wv[7] = hi16(u.w);
        }
#pragma unroll
        for (int i = 0; i < 8; ++i) acc = fmaf(av[i], wv[i], acc);
    }

    const float bb = w32 ? ((const float*)bias)[n] : b2f(((const u16*)bias)[n]);
    const float v = fmaxf(acc + bb, 0.0f);
    const size_t idx = (size_t)m * Dm + n;
    if (o32) ((float*)out)[idx] = v;
    else     ((u16*)out)[idx]  = f2b(v);
}

// ---------------------------------------------------------------------------
// Causal attention, pure VALU. One 64-thread block (1 wave) per (b,h,qrow).
// Lane j scores key kt*64+j (dot over 64 dims, q-row staged in LDS); online
// softmax across the tile via shuffles; p transposed through LDS; lane t then
// accumulates output dim t. Q,K,V,Y are bf16 [B*S, D] with heads in D.
// ---------------------------------------------------------------------------
__global__ __launch_bounds__(64)
void vattn(const u16* __restrict__ Q, const u16* __restrict__ K,
           const u16* __restrict__ V, u16* __restrict__ Y)
{
    __shared__ float qs[64];
    __shared__ float ps[64];

    const int t  = threadIdx.x;
    const int gz = blockIdx.x;          // b*16384 + h*1024 + q
    const int q  = gz & 1023;
    const int h  = (gz >> 10) & 15;
    const int b  = gz >> 14;

    const size_t qoff = ((size_t)(b * S + q)) * Dm + h * HD;
    qs[t] = b2f(Q[qoff + t]);
    __syncthreads();

    float m_i = -1e30f, l_i = 0.0f, o = 0.0f;
    const int ntile = (q >> 6) + 1;

    for (int kt = 0; kt < ntile; ++kt) {
        const int key = kt * 64 + t;
        // score for this lane's key
        const u16* Kr = K + ((size_t)(b * S + key)) * Dm + h * HD;
        float s = 0.0f;
#pragma unroll
        for (int d = 0; d < 64; d += 8) {
            const uint4 u = *(const uint4*)(Kr + d);
            s = fmaf(qs[d + 0], lo16(u.x), s); s = fmaf(qs[d + 1], hi16(u.x), s);
            s = fmaf(qs[d + 2], lo16(u.y), s); s = fmaf(qs[d + 3], hi16(u.y), s);
            s = fmaf(qs[d + 4], lo16(u.z), s); s = fmaf(qs[d + 5], hi16(u.z), s);
            s = fmaf(qs[d + 6], lo16(u.w), s); s = fmaf(qs[d + 7], hi16(u.w), s);
        }
        s *= 0.125f;                      // 1/sqrt(64)
        if (key > q) s = -1e9f;           // causal mask, post-scale like ref

        // tile max + online softmax (reductions over all 64 lanes)
        float mx = s;
#pragma unroll
        for (int off = 1; off < 64; off <<= 1) mx = fmaxf(mx, __shfl_xor(mx, off, 64));
        const float mnew = fmaxf(m_i, mx);
        const float p = __expf(s - mnew);
        float sum = p;
#pragma unroll
        for (int off = 1; off < 64; off <<= 1) sum += __shfl_xor(sum, off, 64);
        const float al = __expf(m_i - mnew);
        l_i = l_i * al + sum;
        m_i = mnew;

        // transpose p (lane=key -> LDS), then lane t accumulates output dim t
        __syncthreads();
        ps[t] = p;
        __syncthreads();
        o *= al;
        const u16* Vb = V + ((size_t)(b * S + kt * 64)) * Dm + h * HD + t;
#pragma unroll 8
        for (int j = 0; j < 64; ++j)
            o = fmaf(ps[j], b2f(Vb[(size_t)j * Dm]), o);
    }

    Y[qoff + t] = f2b(o / l_i);
}

// ---------------------------------------------------------------------------
extern "C" void kernel_launch(void* const* d_in, const int* in_sizes, int n_in,
                              void* d_out, int out_size, void* d_ws, size_t ws_size,
                              hipStream_t stream)
{
    int* flag = (int*)d_ws;
    u16* base = (u16*)((char*)d_ws + 4096);
    const size_t SEG = (size_t)4 * 1024 * 1024;   // 4M elems (8 MB) per region
    u16* vq = base;
    u16* vk = base + SEG;
    u16* vv = base + 2 * SEG;
    u16* vy = base + 3 * SEG;

    probe_dtype<<<1, 1, 0, stream>>>((const unsigned int*)d_in[0], flag);

    dim3 gg(4, 4096), gb(256);
    // q,k,v projections: external A/W/bias, bf16 ws out
    vgemm<<<gg, gb, 0, stream>>>(d_in[0], d_in[4], d_in[5], vq, flag, 1, 1, 0);
    vgemm<<<gg, gb, 0, stream>>>(d_in[1], d_in[6], d_in[7], vk, flag, 1, 1, 0);
    vgemm<<<gg, gb, 0, stream>>>(d_in[2], d_in[8], d_in[9], vv, flag, 1, 1, 0);
    // d_in[3] = causal tril mask, hardcoded in vattn
    vattn<<<dim3(4 * NH * S), dim3(64), 0, stream>>>(vq, vk, vv, vy);
    // out projection: ws A (bf16), external W/bias, d_out follows external dtype
    vgemm<<<gg, gb, 0, stream>>>(vy, d_in[10], d_in[11], d_out, flag, 0, 1, 1);
}